// Round 1
// baseline (1109.897 us; speedup 1.0000x reference)
//
#include <hip/hip_runtime.h>

#define BB  4
#define NN  512
#define DD  128
#define HH1 64
#define HH2 32

__global__ __launch_bounds__(256, 2)
void adj_kernel(const float* __restrict__ v,
                const float* __restrict__ W1,
                const float* __restrict__ b1,
                const float* __restrict__ W2,
                const float* __restrict__ b2,
                const float* __restrict__ W3,
                const float* __restrict__ b3,
                float* __restrict__ out)
{
    __shared__ float vi_s[DD];
    __shared__ float red[8];

    const int blk = blockIdx.x;      // b*N + i
    const int t   = threadIdx.x;

    // stage v_i into LDS (128 floats = 32 float4)
    if (t < DD / 4) {
        const float4* vip = (const float4*)(v + (size_t)blk * DD);
        ((float4*)vi_s)[t] = vip[t];
    }
    __syncthreads();

    const int bbase = blk & ~(NN - 1);   // b*N

    float aj[2];

    #pragma unroll
    for (int jj = 0; jj < 2; ++jj) {
        const int j = t + jj * 256;
        const float4* vj = (const float4*)(v + (size_t)(bbase + j) * DD);

        // ---- layer 1: h1[o] = b1[o] + sum_d W1[o,d] * |vi[d]-vj[d]| ----
        float h1[HH1];
        #pragma unroll
        for (int o = 0; o < HH1; ++o) h1[o] = b1[o];

        #pragma unroll 1   // keep rolled: 16KB hot body stays in I$
        for (int c = 0; c < 4; ++c) {
            float diff[32];
            #pragma unroll
            for (int q = 0; q < 8; ++q) {
                float4 x = vj[c * 8 + q];
                int base = c * 32 + q * 4;
                diff[q * 4 + 0] = fabsf(vi_s[base + 0] - x.x);
                diff[q * 4 + 1] = fabsf(vi_s[base + 1] - x.y);
                diff[q * 4 + 2] = fabsf(vi_s[base + 2] - x.z);
                diff[q * 4 + 3] = fabsf(vi_s[base + 3] - x.w);
            }
            #pragma unroll
            for (int o = 0; o < HH1; ++o) {
                const float* w = W1 + o * DD + c * 32;  // wave-uniform -> s_load
                float acc = h1[o];
                #pragma unroll
                for (int q = 0; q < 32; ++q)
                    acc = fmaf(w[q], diff[q], acc);
                h1[o] = acc;
            }
        }

        // ---- layer 2: h2[c2] = b2[c2] + sum_o W2[c2,o] * leaky(h1[o]) ----
        float h2[HH2];
        #pragma unroll
        for (int c2 = 0; c2 < HH2; ++c2) h2[c2] = b2[c2];

        #pragma unroll
        for (int o = 0; o < HH1; ++o) {
            float ho = h1[o];
            ho = fmaxf(ho, 0.1f * ho);           // leaky relu, branch-free
            #pragma unroll
            for (int c2 = 0; c2 < HH2; ++c2)
                h2[c2] = fmaf(W2[c2 * HH1 + o], ho, h2[c2]);
        }

        // ---- layer 3: a = b3 + sum_c W3[c] * leaky(h2[c]) ----
        float a = b3[0];
        #pragma unroll
        for (int c2 = 0; c2 < HH2; ++c2) {
            float hc = h2[c2];
            hc = fmaxf(hc, 0.1f * hc);
            a = fmaf(W3[c2], hc, a);
        }
        aj[jj] = a;
    }

    // ---- fused softmax over j (512 values, 2 per thread) ----
    const int wid  = t >> 6;
    const int lane = t & 63;

    float m = fmaxf(aj[0], aj[1]);
    #pragma unroll
    for (int s = 32; s > 0; s >>= 1)
        m = fmaxf(m, __shfl_xor(m, s, 64));
    if (lane == 0) red[wid] = m;
    __syncthreads();
    const float M = fmaxf(fmaxf(red[0], red[1]), fmaxf(red[2], red[3]));

    float e0 = __expf(aj[0] - M);
    float e1 = __expf(aj[1] - M);
    float s01 = e0 + e1;
    #pragma unroll
    for (int s = 32; s > 0; s >>= 1)
        s01 += __shfl_xor(s01, s, 64);
    if (lane == 0) red[4 + wid] = s01;
    __syncthreads();
    const float S = (red[4] + red[5]) + (red[6] + red[7]);
    const float inv = 1.0f / S;

    float* orow = out + (size_t)blk * NN;
    orow[t]       = e0 * inv;
    orow[t + 256] = e1 * inv;
}

extern "C" void kernel_launch(void* const* d_in, const int* in_sizes, int n_in,
                              void* d_out, int out_size, void* d_ws, size_t ws_size,
                              hipStream_t stream) {
    const float* v  = (const float*)d_in[0];
    const float* W1 = (const float*)d_in[1];
    const float* b1 = (const float*)d_in[2];
    const float* W2 = (const float*)d_in[3];
    const float* b2 = (const float*)d_in[4];
    const float* W3 = (const float*)d_in[5];
    const float* b3 = (const float*)d_in[6];
    float* out = (float*)d_out;

    adj_kernel<<<dim3(BB * NN), dim3(256), 0, stream>>>(v, W1, b1, W2, b2, W3, b3, out);
}

// Round 2
// 547.593 us; speedup vs baseline: 2.0269x; 2.0269x over previous
//
#include <hip/hip_runtime.h>

#define NN  512
#define DD  128
#define HH1 64
#define HH2 32

__global__ __launch_bounds__(256, 2)
void adj_kernel(const float* __restrict__ v,
                const float* __restrict__ W1,
                const float* __restrict__ b1,
                const float* __restrict__ W2,
                const float* __restrict__ b2,
                const float* __restrict__ W3,
                const float* __restrict__ b3,
                float* __restrict__ out)
{
    __shared__ float red[8];

    const int blk = blockIdx.x;          // b*N + i
    const int t   = threadIdx.x;
    const int bbase = blk & ~(NN - 1);   // b*N

    // wave-uniform pointer -> scalar loads on the scalar pipe
    const float* __restrict__ vi = v + (size_t)blk * DD;

    float aj0, aj1;

    #pragma unroll
    for (int jj = 0; jj < 2; ++jj) {
        const int j = t + (jj << 8);
        const float4* __restrict__ vj4 =
            (const float4*)(v + (size_t)(bbase + j) * DD);

        // ---- diff[128] = |vi - vj|, fully register-resident (static idx) ----
        float diff[DD];
        #pragma unroll
        for (int q = 0; q < DD / 4; ++q) {
            float4 x = vj4[q];
            diff[4 * q + 0] = fabsf(vi[4 * q + 0] - x.x);
            diff[4 * q + 1] = fabsf(vi[4 * q + 1] - x.y);
            diff[4 * q + 2] = fabsf(vi[4 * q + 2] - x.z);
            diff[4 * q + 3] = fabsf(vi[4 * q + 3] - x.w);
        }

        float h2[HH2];
        #pragma unroll
        for (int c = 0; c < HH2; ++c) h2[c] = b2[c];

        // ---- layer 1 in o-chunks of 4, fused immediately into layer 2 ----
        // rolled: keeps the hoistable weight batch small (512 floats/iter)
        #pragma unroll 1
        for (int oc = 0; oc < HH1; oc += 4) {
            const float* __restrict__ w0 = W1 + (size_t)(oc + 0) * DD;
            const float* __restrict__ w1 = W1 + (size_t)(oc + 1) * DD;
            const float* __restrict__ w2 = W1 + (size_t)(oc + 2) * DD;
            const float* __restrict__ w3 = W1 + (size_t)(oc + 3) * DD;
            float a0 = b1[oc + 0];
            float a1 = b1[oc + 1];
            float a2 = b1[oc + 2];
            float a3 = b1[oc + 3];
            #pragma unroll
            for (int d = 0; d < DD; ++d) {
                float x = diff[d];
                a0 = fmaf(w0[d], x, a0);
                a1 = fmaf(w1[d], x, a1);
                a2 = fmaf(w2[d], x, a2);
                a3 = fmaf(w3[d], x, a3);
            }
            // leaky relu, branch-free
            a0 = fmaxf(a0, 0.1f * a0);
            a1 = fmaxf(a1, 0.1f * a1);
            a2 = fmaxf(a2, 0.1f * a2);
            a3 = fmaxf(a3, 0.1f * a3);
            // fold this o-chunk into h2 right away (h1 never fully lives)
            #pragma unroll
            for (int c = 0; c < HH2; ++c) {
                const float* __restrict__ wr = W2 + c * HH1 + oc;
                h2[c] = fmaf(wr[0], a0,
                        fmaf(wr[1], a1,
                        fmaf(wr[2], a2,
                        fmaf(wr[3], a3, h2[c]))));
            }
        }

        // ---- layer 3 ----
        float a = b3[0];
        #pragma unroll
        for (int c = 0; c < HH2; ++c) {
            float hc = h2[c];
            hc = fmaxf(hc, 0.1f * hc);
            a = fmaf(W3[c], hc, a);
        }
        if (jj == 0) aj0 = a; else aj1 = a;
    }

    // ---- fused softmax over j (512 values, 2 per thread) ----
    const int wid  = t >> 6;
    const int lane = t & 63;

    float m = fmaxf(aj0, aj1);
    #pragma unroll
    for (int s = 32; s > 0; s >>= 1)
        m = fmaxf(m, __shfl_xor(m, s, 64));
    if (lane == 0) red[wid] = m;
    __syncthreads();
    const float M = fmaxf(fmaxf(red[0], red[1]), fmaxf(red[2], red[3]));

    float e0 = __expf(aj0 - M);
    float e1 = __expf(aj1 - M);
    float s01 = e0 + e1;
    #pragma unroll
    for (int s = 32; s > 0; s >>= 1)
        s01 += __shfl_xor(s01, s, 64);
    if (lane == 0) red[4 + wid] = s01;
    __syncthreads();
    const float S = (red[4] + red[5]) + (red[6] + red[7]);
    const float inv = 1.0f / S;

    float* orow = out + (size_t)blk * NN;
    orow[t]       = e0 * inv;
    orow[t + 256] = e1 * inv;
}

extern "C" void kernel_launch(void* const* d_in, const int* in_sizes, int n_in,
                              void* d_out, int out_size, void* d_ws, size_t ws_size,
                              hipStream_t stream) {
    const float* v  = (const float*)d_in[0];
    const float* W1 = (const float*)d_in[1];
    const float* b1 = (const float*)d_in[2];
    const float* W2 = (const float*)d_in[3];
    const float* b2 = (const float*)d_in[4];
    const float* W3 = (const float*)d_in[5];
    const float* b3 = (const float*)d_in[6];
    float* out = (float*)d_out;

    adj_kernel<<<dim3(4 * NN), dim3(256), 0, stream>>>(v, W1, b1, W2, b2, W3, b3, out);
}

// Round 3
// 238.872 us; speedup vs baseline: 4.6464x; 2.2924x over previous
//
#include <hip/hip_runtime.h>

#define NN  512
#define DD  128

typedef __attribute__((ext_vector_type(4)))  float f32x4;
typedef __attribute__((ext_vector_type(8)))  short s16x8;   // 8 bf16 (4 VGPRs)

// fp32 -> (bf16 hi [RNE], bf16 lo [trunc of remainder]); packed as short8 frags
__device__ inline void split8(const float* __restrict__ x, s16x8& h, s16x8& l) {
    unsigned hw[8], lw[8];
    #pragma unroll
    for (int i = 0; i < 8; ++i) {
        unsigned u  = __float_as_uint(x[i]);
        unsigned hr = (u + 0x7FFFu + ((u >> 16) & 1u)) >> 16;   // RNE bf16
        float    hf = __uint_as_float(hr << 16);
        float    lo = x[i] - hf;
        unsigned lr = __float_as_uint(lo) >> 16;                // trunc bf16
        hw[i] = hr & 0xFFFFu;
        lw[i] = lr & 0xFFFFu;
    }
    uint4 hp, lp;
    hp.x = hw[0] | (hw[1] << 16);  hp.y = hw[2] | (hw[3] << 16);
    hp.z = hw[4] | (hw[5] << 16);  hp.w = hw[6] | (hw[7] << 16);
    lp.x = lw[0] | (lw[1] << 16);  lp.y = lw[2] | (lw[3] << 16);
    lp.z = lw[4] | (lw[5] << 16);  lp.w = lw[6] | (lw[7] << 16);
    h = __builtin_bit_cast(s16x8, hp);
    l = __builtin_bit_cast(s16x8, lp);
}

#define MFMA(a, b, c) __builtin_amdgcn_mfma_f32_16x16x32_bf16((a), (b), (c), 0, 0, 0)

// H1 LDS row stride: 68 floats -> 272 B (16B-aligned for b128, 4m+o banks: 2-way max)
#define H1S 68

__global__ __launch_bounds__(256, 2)
void adj_mfma(const float* __restrict__ v,
              const float* __restrict__ W1,
              const float* __restrict__ b1,
              const float* __restrict__ W2,
              const float* __restrict__ b2,
              const float* __restrict__ W3,
              const float* __restrict__ b3,
              float* __restrict__ out)
{
    __shared__ float vi_s[DD];
    __shared__ float h1_s[128 * H1S];   // 34.0 KB: 128 rows x 64 o (fp32, leaky applied)
    __shared__ float logits[NN];
    __shared__ float red[8];

    const int blk   = blockIdx.x;        // b*N + i
    const int t     = threadIdx.x;
    const int w     = t >> 6;            // wave 0..3
    const int l     = t & 63;
    const int m16   = l & 15;            // MFMA row/col-in-tile lane field
    const int q     = l >> 4;            // quad 0..3
    const int bbase = blk & ~(NN - 1);

    const int rhalf = w & 1;             // layer1: rows [rhalf*64, +64) of the 128-row slab
    const int ohalf = w >> 1;            // layer1: o in [ohalf*32, +32)

    // ---- stage v_i ----
    if (t < DD / 4)
        ((float4*)vi_s)[t] = ((const float4*)(v + (size_t)blk * DD))[t];
    __syncthreads();

    // ---- build resident B-frags (per-wave, from global; L1/L2-hot) ----
    // layer1 B: B[k=d][n=o], lane holds B[kt*32+q*8+i][ohalf*32+ot*16+m16]
    s16x8 B1h[2][4], B1l[2][4];
    #pragma unroll
    for (int ot = 0; ot < 2; ++ot)
        #pragma unroll
        for (int kt = 0; kt < 4; ++kt) {
            const float* src = W1 + (size_t)(ohalf * 32 + ot * 16 + m16) * DD + kt * 32 + q * 8;
            float x[8];
            *(float4*)(x)     = *(const float4*)(src);
            *(float4*)(x + 4) = *(const float4*)(src + 4);
            split8(x, B1h[ot][kt], B1l[ot][kt]);
        }
    // layer2 B: B[k=o][n=c2], lane holds W2[ot2*16+m16][kt2*32+q*8+i]
    s16x8 B2h[2][2], B2l[2][2];
    #pragma unroll
    for (int ot2 = 0; ot2 < 2; ++ot2)
        #pragma unroll
        for (int kt2 = 0; kt2 < 2; ++kt2) {
            const float* src = W2 + (size_t)(ot2 * 16 + m16) * 64 + kt2 * 32 + q * 8;
            float x[8];
            *(float4*)(x)     = *(const float4*)(src);
            *(float4*)(x + 4) = *(const float4*)(src + 4);
            split8(x, B2h[ot2][kt2], B2l[ot2][kt2]);
        }

    const float bia0 = b1[ohalf * 32 + m16];        // layer1 bias for ot=0 col
    const float bia1 = b1[ohalf * 32 + 16 + m16];   // ot=1 col
    const float b2v0 = b2[m16];                     // layer2 bias ot2=0
    const float b2v1 = b2[16 + m16];                // ot2=1
    const float w3v0 = W3[m16];
    const float w3v1 = W3[16 + m16];
    const float b3v  = b3[0];

    // ---- main loop: 4 super-tiles of 128 j-rows ----
    for (int st = 0; st < 4; ++st) {
        // ======== layer 1 ========
        #pragma unroll 1
        for (int mt = 0; mt < 4; ++mt) {
            const int lrow = rhalf * 64 + mt * 16 + m16;         // row in slab
            const float* vr = v + (size_t)(bbase + st * 128 + lrow) * DD;

            f32x4 c0 = {0.f, 0.f, 0.f, 0.f};
            f32x4 c1 = {0.f, 0.f, 0.f, 0.f};

            #pragma unroll
            for (int kt = 0; kt < 4; ++kt) {
                float4 x0 = *(const float4*)(vr + kt * 32 + q * 8);
                float4 x1 = *(const float4*)(vr + kt * 32 + q * 8 + 4);
                float4 y0 = *(const float4*)(vi_s + kt * 32 + q * 8);
                float4 y1 = *(const float4*)(vi_s + kt * 32 + q * 8 + 4);
                float d8[8];
                d8[0] = fabsf(y0.x - x0.x);  d8[1] = fabsf(y0.y - x0.y);
                d8[2] = fabsf(y0.z - x0.z);  d8[3] = fabsf(y0.w - x0.w);
                d8[4] = fabsf(y1.x - x1.x);  d8[5] = fabsf(y1.y - x1.y);
                d8[6] = fabsf(y1.z - x1.z);  d8[7] = fabsf(y1.w - x1.w);
                s16x8 ah, al;
                split8(d8, ah, al);
                // 3-pass split product: hh + hl + lh (ll dropped, ~2^-17 rel)
                c0 = MFMA(ah, B1h[0][kt], c0);
                c0 = MFMA(ah, B1l[0][kt], c0);
                c0 = MFMA(al, B1h[0][kt], c0);
                c1 = MFMA(ah, B1h[1][kt], c1);
                c1 = MFMA(ah, B1l[1][kt], c1);
                c1 = MFMA(al, B1h[1][kt], c1);
            }
            // bias + leaky + store to LDS (C layout: row=q*4+r, col=m16)
            #pragma unroll
            for (int r = 0; r < 4; ++r) {
                const int rr = rhalf * 64 + mt * 16 + q * 4 + r;
                float h0 = c0[r] + bia0;  h0 = fmaxf(h0, 0.1f * h0);
                float h1v = c1[r] + bia1; h1v = fmaxf(h1v, 0.1f * h1v);
                h1_s[rr * H1S + ohalf * 32 + m16]      = h0;
                h1_s[rr * H1S + ohalf * 32 + 16 + m16] = h1v;
            }
        }
        __syncthreads();

        // ======== layer 2 + 3 ======== (wave owns local rows [w*32, +32))
        #pragma unroll
        for (int mt2 = 0; mt2 < 2; ++mt2) {
            const int lm = w * 32 + mt2 * 16 + m16;   // A-frag row
            f32x4 d0 = {0.f, 0.f, 0.f, 0.f};
            f32x4 d1 = {0.f, 0.f, 0.f, 0.f};
            #pragma unroll
            for (int kt2 = 0; kt2 < 2; ++kt2) {
                const float* hp = h1_s + lm * H1S + kt2 * 32 + q * 8;
                float a8[8];
                *(float4*)(a8)     = *(const float4*)(hp);
                *(float4*)(a8 + 4) = *(const float4*)(hp + 4);
                s16x8 ah, al;
                split8(a8, ah, al);
                d0 = MFMA(ah, B2h[0][kt2], d0);
                d0 = MFMA(ah, B2l[0][kt2], d0);
                d0 = MFMA(al, B2h[0][kt2], d0);
                d1 = MFMA(ah, B2h[1][kt2], d1);
                d1 = MFMA(ah, B2l[1][kt2], d1);
                d1 = MFMA(al, B2h[1][kt2], d1);
            }
            // layer3: lane col c2 = ot2*16+m16; rows q*4+r. Reduce over c2 lanes.
            #pragma unroll
            for (int r = 0; r < 4; ++r) {
                float h0 = d0[r] + b2v0;  h0 = fmaxf(h0, 0.1f * h0);
                float h1v = d1[r] + b2v1; h1v = fmaxf(h1v, 0.1f * h1v);
                float s = w3v0 * h0 + w3v1 * h1v;
                s += __shfl_xor(s, 1, 64);
                s += __shfl_xor(s, 2, 64);
                s += __shfl_xor(s, 4, 64);
                s += __shfl_xor(s, 8, 64);
                if (m16 == 0)
                    logits[st * 128 + w * 32 + mt2 * 16 + q * 4 + r] = s + b3v;
            }
        }
        __syncthreads();
    }

    // ---- fused softmax over 512 logits ----
    const int lane = l;
    float a0 = logits[t];
    float a1 = logits[t + 256];

    float m = fmaxf(a0, a1);
    #pragma unroll
    for (int s = 32; s > 0; s >>= 1)
        m = fmaxf(m, __shfl_xor(m, s, 64));
    if (lane == 0) red[w] = m;
    __syncthreads();
    const float M = fmaxf(fmaxf(red[0], red[1]), fmaxf(red[2], red[3]));

    float e0 = __expf(a0 - M);
    float e1 = __expf(a1 - M);
    float s01 = e0 + e1;
    #pragma unroll
    for (int s = 32; s > 0; s >>= 1)
        s01 += __shfl_xor(s01, s, 64);
    if (lane == 0) red[4 + w] = s01;
    __syncthreads();
    const float S = (red[4] + red[5]) + (red[6] + red[7]);
    const float inv = 1.0f / S;

    float* orow = out + (size_t)blk * NN;
    orow[t]       = e0 * inv;
    orow[t + 256] = e1 * inv;
}

extern "C" void kernel_launch(void* const* d_in, const int* in_sizes, int n_in,
                              void* d_out, int out_size, void* d_ws, size_t ws_size,
                              hipStream_t stream) {
    const float* v  = (const float*)d_in[0];
    const float* W1 = (const float*)d_in[1];
    const float* b1 = (const float*)d_in[2];
    const float* W2 = (const float*)d_in[3];
    const float* b2 = (const float*)d_in[4];
    const float* W3 = (const float*)d_in[5];
    const float* b3 = (const float*)d_in[6];
    float* out = (float*)d_out;

    adj_mfma<<<dim3(4 * NN), dim3(256), 0, stream>>>(v, W1, b1, W2, b2, W3, b3, out);
}

// Round 4
// 168.699 us; speedup vs baseline: 6.5792x; 1.4160x over previous
//
#include <hip/hip_runtime.h>

#define NN  512
#define DD  128

typedef __attribute__((ext_vector_type(4))) float f32x4;
typedef __attribute__((ext_vector_type(8))) short s16x8;   // 8 bf16 (4 VGPRs)

#define MFMA(a, b, c) __builtin_amdgcn_mfma_f32_16x16x32_bf16((a), (b), (c), 0, 0, 0)

// LDS strides (ushort units for B, float units for h1): padded to break
// power-of-2 banks -> worst 2-way (free, m136)
#define B1S 136   // 128 + 8
#define B2S 72    // 64 + 8
#define H1S 68    // 64 + 4

// fp32 -> (bf16 hi [round-to-nearest-away], bf16 lo [trunc of exact remainder])
// 8 elems -> two packed s16x8 frags. ~4 VALU/elem via v_perm_b32 packing.
// Product hh+hl+lh captures A*B to ~2^-17 rel (dropped ll <= 2^-18).
__device__ inline void split8(const float* __restrict__ x, s16x8& h, s16x8& l) {
    uint4 hp, lp;
    unsigned* hw = (unsigned*)&hp;
    unsigned* lw = (unsigned*)&lp;
    #pragma unroll
    for (int i = 0; i < 4; ++i) {
        float x0 = x[2 * i], x1 = x[2 * i + 1];
        unsigned t0 = __float_as_uint(x0) + 0x8000u;   // RNA in bf16 position
        unsigned t1 = __float_as_uint(x1) + 0x8000u;
        // pack [t0.hi16, t1.hi16] -> one u32 (low short = elem0)
        hw[i] = __builtin_amdgcn_perm(t1, t0, 0x07060302u);
        float l0 = x0 - __uint_as_float(t0 & 0xFFFF0000u);   // exact remainder
        float l1 = x1 - __uint_as_float(t1 & 0xFFFF0000u);
        // trunc-pack lo (error <= 2^-17 |x|)
        lw[i] = __builtin_amdgcn_perm(__float_as_uint(l1), __float_as_uint(l0), 0x07060302u);
    }
    h = __builtin_bit_cast(s16x8, hp);
    l = __builtin_bit_cast(s16x8, lp);
}

__device__ inline void split1(float x, unsigned short& hs, unsigned short& ls) {
    unsigned t = __float_as_uint(x) + 0x8000u;
    hs = (unsigned short)(t >> 16);
    float lo = x - __uint_as_float(t & 0xFFFF0000u);
    ls = (unsigned short)(__float_as_uint(lo) >> 16);
}

__global__ __launch_bounds__(256, 2)
void adj_mfma2(const float* __restrict__ v,
               const float* __restrict__ W1,
               const float* __restrict__ b1,
               const float* __restrict__ W2,
               const float* __restrict__ b2,
               const float* __restrict__ W3,
               const float* __restrict__ b3,
               float* __restrict__ out)
{
    // 63.5 KB total -> 2 blocks/CU; h1_s rows are WAVE-PRIVATE (no barriers)
    __shared__ __attribute__((aligned(16))) unsigned short B1h_s[64 * B1S];
    __shared__ __attribute__((aligned(16))) unsigned short B1l_s[64 * B1S];
    __shared__ __attribute__((aligned(16))) unsigned short B2h_s[32 * B2S];
    __shared__ __attribute__((aligned(16))) unsigned short B2l_s[32 * B2S];
    __shared__ __attribute__((aligned(16))) float h1_s[64 * H1S];
    __shared__ float logits[NN];
    __shared__ float red[8];

    const int blk   = blockIdx.x;        // b*N + i
    const int t     = threadIdx.x;
    const int w     = t >> 6;            // wave 0..3
    const int m16   = t & 15;            // MFMA lane field (row for A, col for B/C)
    const int q     = (t & 63) >> 4;     // quad 0..3
    const int q8    = q * 8;
    const int bbase = blk & ~(NN - 1);

    // ---- prologue: split W1/W2 into LDS (once per block), coalesced ----
    #pragma unroll
    for (int e = 0; e < 32; ++e) {       // W1: 64x128 = 8192 elems
        int idx = e * 256 + t;
        unsigned short hs, ls;
        split1(W1[idx], hs, ls);
        int o = idx >> 7, d = idx & 127;
        B1h_s[o * B1S + d] = hs;
        B1l_s[o * B1S + d] = ls;
    }
    #pragma unroll
    for (int e = 0; e < 8; ++e) {        // W2: 32x64 = 2048 elems
        int idx = e * 256 + t;
        unsigned short hs, ls;
        split1(W2[idx], hs, ls);
        int c2 = idx >> 6, k = idx & 63;
        B2h_s[c2 * B2S + k] = hs;
        B2l_s[c2 * B2S + k] = ls;
    }

    // per-lane constants & v_i slices (registers; v_i shared by all j)
    float b1v[4];
    #pragma unroll
    for (int ot = 0; ot < 4; ++ot) b1v[ot] = b1[ot * 16 + m16];
    const float b2v0 = b2[m16];
    const float b2v1 = b2[16 + m16];
    const float w3v0 = W3[m16];
    const float w3v1 = W3[16 + m16];
    const float b3v  = b3[0];

    const float* __restrict__ vip = v + (size_t)blk * DD;
    float yv[4][8];
    #pragma unroll
    for (int kt = 0; kt < 4; ++kt) {
        *(float4*)&yv[kt][0] = *(const float4*)(vip + kt * 32 + q8);
        *(float4*)&yv[kt][4] = *(const float4*)(vip + kt * 32 + q8 + 4);
    }

    __syncthreads();   // B1/B2 ready; ONLY barrier before the softmax one

    // ---- main loop: 8 slabs of 64 j-rows; wave owns rows [w*16, w*16+16) ----
    const size_t rowbase = (size_t)(bbase + w * 16 + m16) * DD;

    #pragma unroll 1
    for (int st = 0; st < 8; ++st) {
        const float* __restrict__ vr = v + rowbase + (size_t)st * 64 * DD;

        // lane's A-row slice (row = st*64 + w*16 + m16, k = kt*32+q8..+7)
        float xr[4][8];
        #pragma unroll
        for (int kt = 0; kt < 4; ++kt) {
            *(float4*)&xr[kt][0] = *(const float4*)(vr + kt * 32 + q8);
            *(float4*)&xr[kt][4] = *(const float4*)(vr + kt * 32 + q8 + 4);
        }

        // ======== layer 1: 16 rows x 64 cols, K=128 ========
        f32x4 c[4];
        #pragma unroll
        for (int ot = 0; ot < 4; ++ot) c[ot] = (f32x4){0.f, 0.f, 0.f, 0.f};

        #pragma unroll
        for (int kt = 0; kt < 4; ++kt) {
            float d8[8];
            #pragma unroll
            for (int i = 0; i < 8; ++i) d8[i] = fabsf(yv[kt][i] - xr[kt][i]);
            s16x8 ah, al;
            split8(d8, ah, al);                    // 1 split feeds 12 MFMAs
            #pragma unroll
            for (int ot = 0; ot < 4; ++ot) {
                const int n = ot * 16 + m16;
                s16x8 bh = *(const s16x8*)(B1h_s + n * B1S + kt * 32 + q8);
                s16x8 bl = *(const s16x8*)(B1l_s + n * B1S + kt * 32 + q8);
                c[ot] = MFMA(ah, bh, c[ot]);
                c[ot] = MFMA(al, bh, c[ot]);
                c[ot] = MFMA(ah, bl, c[ot]);
            }
        }

        // bias + leaky -> h1 rows [w*16, +16): written AND later read by this
        // wave only -> no __syncthreads needed (compiler emits lgkmcnt wait)
        #pragma unroll
        for (int ot = 0; ot < 4; ++ot)
            #pragma unroll
            for (int r = 0; r < 4; ++r) {
                float hv = c[ot][r] + b1v[ot];
                hv = fmaxf(hv, 0.1f * hv);
                h1_s[(w * 16 + q * 4 + r) * H1S + ot * 16 + m16] = hv;
            }

        // ======== layer 2: same 16 rows, 32 cols, K=64 ========
        f32x4 dacc[2];
        dacc[0] = (f32x4){0.f, 0.f, 0.f, 0.f};
        dacc[1] = (f32x4){0.f, 0.f, 0.f, 0.f};
        #pragma unroll
        for (int kt2 = 0; kt2 < 2; ++kt2) {
            const float* hp = h1_s + (w * 16 + m16) * H1S + kt2 * 32 + q8;
            float a8[8];
            *(float4*)&a8[0] = *(const float4*)(hp);
            *(float4*)&a8[4] = *(const float4*)(hp + 4);
            s16x8 ah, al;
            split8(a8, ah, al);
            #pragma unroll
            for (int ot2 = 0; ot2 < 2; ++ot2) {
                const int n = ot2 * 16 + m16;
                s16x8 bh = *(const s16x8*)(B2h_s + n * B2S + kt2 * 32 + q8);
                s16x8 bl = *(const s16x8*)(B2l_s + n * B2S + kt2 * 32 + q8);
                dacc[ot2] = MFMA(ah, bh, dacc[ot2]);
                dacc[ot2] = MFMA(al, bh, dacc[ot2]);
                dacc[ot2] = MFMA(ah, bl, dacc[ot2]);
            }
        }

        // ======== layer 3 + 16-lane reduce -> logits ========
        #pragma unroll
        for (int r = 0; r < 4; ++r) {
            float h0 = dacc[0][r] + b2v0;  h0 = fmaxf(h0, 0.1f * h0);
            float h1v = dacc[1][r] + b2v1; h1v = fmaxf(h1v, 0.1f * h1v);
            float s = fmaf(w3v0, h0, w3v1 * h1v);
            s += __shfl_xor(s, 1, 64);
            s += __shfl_xor(s, 2, 64);
            s += __shfl_xor(s, 4, 64);
            s += __shfl_xor(s, 8, 64);
            if (m16 == 0)
                logits[st * 64 + w * 16 + q * 4 + r] = s + b3v;
        }
    }

    __syncthreads();   // logits complete

    // ---- fused softmax over 512 logits ----
    const int lane = t & 63;
    float a0 = logits[t];
    float a1 = logits[t + 256];

    float m = fmaxf(a0, a1);
    #pragma unroll
    for (int s = 32; s > 0; s >>= 1)
        m = fmaxf(m, __shfl_xor(m, s, 64));
    if (lane == 0) red[w] = m;
    __syncthreads();
    const float M = fmaxf(fmaxf(red[0], red[1]), fmaxf(red[2], red[3]));

    float e0 = __expf(a0 - M);
    float e1 = __expf(a1 - M);
    float s01 = e0 + e1;
    #pragma unroll
    for (int s = 32; s > 0; s >>= 1)
        s01 += __shfl_xor(s01, s, 64);
    if (lane == 0) red[4 + w] = s01;
    __syncthreads();
    const float S = (red[4] + red[5]) + (red[6] + red[7]);
    const float inv = 1.0f / S;

    float* orow = out + (size_t)blk * NN;
    orow[t]       = e0 * inv;
    orow[t + 256] = e1 * inv;
}

extern "C" void kernel_launch(void* const* d_in, const int* in_sizes, int n_in,
                              void* d_out, int out_size, void* d_ws, size_t ws_size,
                              hipStream_t stream) {
    const float* v  = (const float*)d_in[0];
    const float* W1 = (const float*)d_in[1];
    const float* b1 = (const float*)d_in[2];
    const float* W2 = (const float*)d_in[3];
    const float* b2 = (const float*)d_in[4];
    const float* W3 = (const float*)d_in[5];
    const float* b3 = (const float*)d_in[6];
    float* out = (float*)d_out;

    adj_mfma2<<<dim3(4 * NN), dim3(256), 0, stream>>>(v, W1, b1, W2, b2, W3, b3, out);
}